// Round 20
// baseline (159.642 us; speedup 1.0000x reference)
//
#include <hip/hip_runtime.h>
#include <math.h>

#define NPG 128      // nodes per graph
#define HID 64
#define ICH 151
#define EPG 2048     // edges per graph
#define TPB 512      // 8 waves
#define EPT (EPG / TPB)
#define KP  160      // W1T padded K (5 MFMA k-steps of 32)
#define HTS 136      // h^T row stride, bf16 (272B: 16B-aligned, 2-way banks)
#define ABS 136      // Ab row stride, bf16 (272B: 16B-aligned, 2-way banks)
#define AB_OFF 17408 // byte offset of Ab region (= ht bytes)
#define GRID 768     // persistent: 3 blocks/CU x 256 CUs

typedef __attribute__((ext_vector_type(8))) short  short8;   // bf16x8 frag
typedef __attribute__((ext_vector_type(4))) float  floatx4;  // f32x4 acc

// software fp32->bf16 RNE (proven R4/R6/R8/R10-R19; cvt_pk asm NaN'd R7/R9)
static __device__ __forceinline__ unsigned short f2bf(float v) {
    unsigned u = __builtin_bit_cast(unsigned, v);
    return (unsigned short)((u + 0x7fffu + ((u >> 16) & 1u)) >> 16);
}
static __device__ __forceinline__ float bf2f(short b) {
    return __builtin_bit_cast(float, ((unsigned)(unsigned short)b) << 16);
}
static __device__ __forceinline__ unsigned packbf(float a, float b) {
    return (unsigned)f2bf(a) | ((unsigned)f2bf(b) << 16);
}
static __device__ __forceinline__ short8 pack8(const float* v) {
    union { unsigned u[4]; short8 s; } r;
    r.u[0] = packbf(v[0], v[1]);
    r.u[1] = packbf(v[2], v[3]);
    r.u[2] = packbf(v[4], v[5]);
    r.u[3] = packbf(v[6], v[7]);
    return r.s;
}

// bf16 += w at linear index idx of a bf16 LDS array (dword CAS; handles dups)
static __device__ __forceinline__ void lds_bf16_add(short* base, int idx, float w) {
    unsigned* a = (unsigned*)base + (idx >> 1);
    unsigned sh = (unsigned)(idx & 1) << 4;
    unsigned cur = *(volatile unsigned*)a;
    for (;;) {
        unsigned old = cur;
        float f = __builtin_bit_cast(float, ((old >> sh) & 0xFFFFu) << 16) + w;
        unsigned nw2 = (old & ~(0xFFFFu << sh)) | ((unsigned)f2bf(f) << sh);
        cur = atomicCAS(a, old, nw2);
        if (cur == old) break;
    }
}

// ---- prep: W1 [151][64] f32 -> W1T [64][160] bf16 (k-pad zeroed) ----
__global__ __launch_bounds__(512) void gcn_prep(const float* __restrict__ W1,
                                                short* __restrict__ W1T) {
    int i = threadIdx.x + blockIdx.x * 512;          // 10240 elements exactly
    if (i < HID * KP) {
        int ch = i / KP, k = i - ch * KP;
        W1T[i] = (short)f2bf((k < ICH) ? W1[k * HID + ch] : 0.0f);
    }
}

__global__ __launch_bounds__(TPB, 6) void gcn_fused(
    const float* __restrict__ x,       // [N,151]
    const int*   __restrict__ erow,    // [E]
    const int*   __restrict__ ecol,    // [E]
    const float* __restrict__ ew,      // [E]
    const short* __restrict__ W1T,     // [64][160] bf16 (prepped)
    const float* __restrict__ b1,      // [64]
    const float* __restrict__ Wlin,    // [8192]
    const float* __restrict__ blin,    // [1]
    float* __restrict__ out,           // [B]
    int B)
{
    // LDS 52224 B + ~0.6KB statics -> 3 blocks/CU (persistent):
    //   ht = smem[0 .. 17408)        64x136 bf16 h^T (GEMM out, agg B-frags)
    //   Ab = smem[17408 .. 52224)    128x136 bf16 FULL raw adjacency
    __shared__ __align__(16) char smem[AB_OFF + NPG * ABS * 2];
    __shared__ float deg[NPG];
    __shared__ float red[TPB / 64];

    short* ht = (short*)smem;
    short* Ab = (short*)(smem + AB_OFF);

    const int t    = threadIdx.x;
    const int lane = t & 63;
    const int wv   = t >> 6;
    const int c16  = lane & 15;
    const int kq   = (lane >> 4) * 8;

    const int arow  = wv * 16 + c16;                   // agg A-frag dst row
    const int rbase = wv * 16 + (lane >> 4) * 4;       // agg D rows (dst nodes)

    // ============ persistent loop: 2-3 graphs per block ============
    // Per-iteration register state is ONLY af[5] (R18's spill came from
    // ep_/nw_/v0 arrays carried across barriers — all eliminated here).
    for (int g = blockIdx.x; g < B; g += GRID) {

        // ---- phase A: deg init + zero Ab with fused diagonal ----
        __syncthreads();                               // bar0: prev iter fully read
        if (t < NPG) deg[t] = 1.0f;                    // self-loop weight
        for (int p = t; p < NPG * ABS / 8; p += TPB) {
            union { int4 i4; short s[8]; } c;
            c.i4 = make_int4(0, 0, 0, 0);
            int i = (8 * p + 136) / 137;               // candidate diag row
            int d = i * 137 - 8 * p;
            if (i < NPG && d >= 0 && d < 8)
                c.s[d] = (short)0x3F80;                // bf16 1.0
            *(int4*)&Ab[p * 8] = c.i4;
        }
        __syncthreads();                               // bar1: Ab/deg ready

        // ---- phase B: x frags + edge pass (load+atomics inline) + GEMM ----
        short8 af[5];
        {
            const float* xr = x + (size_t)g * (NPG * ICH) + (wv * 16 + c16) * ICH;
            #pragma unroll
            for (int s = 0; s < 5; ++s) {
                float v[8];
                #pragma unroll
                for (int j = 0; j < 8; ++j) {
                    int k = s * 32 + kq + j;
                    v[j] = (k < ICH) ? xr[k] : 0.0f;
                }
                af[s] = pack8(v);
            }
        }

        const int ebase = g * EPG;
        #pragma unroll
        for (int it = 0; it < EPT; ++it) {             // edges: load & consume
            int e  = ebase + t + it * TPB;
            int rl = erow[e] & (NPG - 1);
            int cl = ecol[e] & (NPG - 1);
            float w = ew[e];
            atomicAdd(&deg[cl], w);
            lds_bf16_add(Ab, cl * ABS + rl, w);
        }

        #pragma unroll
        for (int n = 0; n < 4; ++n) {                  // GEMM h = x @ W1 -> ht
            floatx4 acc = {0.0f, 0.0f, 0.0f, 0.0f};
            #pragma unroll
            for (int s = 0; s < 5; ++s) {
                short8 b = *(const short8*)&W1T[(n * 16 + c16) * KP + s * 32 + kq];
                acc = __builtin_amdgcn_mfma_f32_16x16x32_bf16(af[s], b, acc, 0, 0, 0);
            }
            int col = n * 16 + c16;
            int row = wv * 16 + (lane >> 4) * 4;
            *(int2*)&ht[col * HTS + row] =
                make_int2((int)packbf(acc[0], acc[1]), (int)packbf(acc[2], acc[3]));
        }
        __syncthreads();                               // bar2: deg/Ab/ht final

        // ---- phase C: single agg pass, K=128 ----
        short8 afr[4];                                 // dinv[src]-scaled A-frags
        #pragma unroll
        for (int ks = 0; ks < 4; ++ks) {
            short8 a = *(const short8*)&Ab[arow * ABS + ks * 32 + kq];
            float v[8];
            #pragma unroll
            for (int j = 0; j < 8; ++j)
                v[j] = bf2f(a[j]) * rsqrtf(deg[ks * 32 + kq + j]);
            afr[ks] = pack8(v);
        }
        float rs[4];
        #pragma unroll
        for (int r = 0; r < 4; ++r)                    // dinv[dst] row scale
            rs[r] = rsqrtf(deg[rbase + r]);

        float partial = 0.0f;
        #pragma unroll
        for (int nt = 0; nt < 4; ++nt) {
            int col = nt * 16 + c16;
            floatx4 acc = {0.0f, 0.0f, 0.0f, 0.0f};
            #pragma unroll
            for (int ks = 0; ks < 4; ++ks) {
                short8 b = *(const short8*)&ht[col * HTS + ks * 32 + kq];
                acc = __builtin_amdgcn_mfma_f32_16x16x32_bf16(afr[ks], b, acc, 0, 0, 0);
            }
            float b1v = b1[col];
            #pragma unroll
            for (int r = 0; r < 4; ++r) {
                float v = fmaxf(acc[r] * rs[r] + b1v, 0.0f);
                partial += v * Wlin[(rbase + r) * HID + col];
            }
        }

        #pragma unroll
        for (int o = 32; o > 0; o >>= 1)
            partial += __shfl_down(partial, o, 64);
        if (lane == 0) red[wv] = partial;
        __syncthreads();                               // bar3: red ready
        if (t == 0) {
            float tot = blin[0];
            #pragma unroll
            for (int i = 0; i < TPB / 64; ++i) tot += red[i];
            out[g] = 1.0f / (1.0f + expf(-tot));
        }
    }
}

extern "C" void kernel_launch(void* const* d_in, const int* in_sizes, int n_in,
                              void* d_out, int out_size, void* d_ws, size_t ws_size,
                              hipStream_t stream) {
    const float* x    = (const float*)d_in[0];
    const int*   ei   = (const int*)d_in[1];
    const float* ew   = (const float*)d_in[2];
    const float* W1   = (const float*)d_in[4];
    const float* b1   = (const float*)d_in[5];
    const float* Wlin = (const float*)d_in[6];
    const float* blin = (const float*)d_in[7];
    float* out = (float*)d_out;

    const int E = in_sizes[1] / 2;     // edge_index is [2, E]
    const int B = out_size;            // 2048 graphs

    short* W1T = (short*)d_ws;         // [64][160] bf16 = 20480 B

    gcn_prep<<<(HID * KP + 511) / 512, 512, 0, stream>>>(W1, W1T);
    gcn_fused<<<GRID, TPB, 0, stream>>>(x, ei, ei + E, ew, W1T, b1, Wlin, blin,
                                        out, B);
}